// Round 8
// baseline (328.307 us; speedup 1.0000x reference)
//
#include <hip/hip_runtime.h>
#include <hip/hip_bf16.h>

#define EPSF 1e-5f

typedef __bf16 bf16x8 __attribute__((ext_vector_type(8)));
typedef float  f32x4  __attribute__((ext_vector_type(4)));
#define MFMA16(a, b, c) __builtin_amdgcn_mfma_f32_16x16x32_bf16((a), (b), (c), 0, 0, 0)

__device__ __forceinline__ bf16x8 ld_bf8(const __bf16* p) { return *(const bf16x8*)p; }

__device__ __forceinline__ unsigned short f2bf(float x) {
    unsigned int u = __float_as_uint(x);
    unsigned int r = (u + 0x7fffu + ((u >> 16) & 1u)) >> 16;
    return (unsigned short)r;
}

// Packed fragment layout: [n>>4][k>>5][(k>>3)&3][n&15][k&7]
// -> per (16-col tile, 32-k slice) one wave B-fragment = 1024 contiguous bytes.
__device__ __forceinline__ size_t pk_idx(int n, int k, int K) {
    return ((size_t)(((n >> 4) * (K >> 5) + (k >> 5)) * 4 + ((k >> 3) & 3)) * 16
            + (n & 15)) * 8 + (k & 7);
}

// ============================================================================
// setupA: gn_partial | ts(=style@Ws) | wtrans x7 (wq,wo,wk,wv,wp2,wf1,wf2)
// grid = 1024 + 16 + 64*5 + 128*2 = 1616
// ============================================================================
__device__ void wtrans_body(const float* __restrict__ W, unsigned short* __restrict__ Wt,
                            int K, int N, int L, int t, float* tile /*32x33*/) {
    int ktiles = K >> 5;
    int kt = L % ktiles, ntl = L / ktiles;
    int k0 = kt * 32, n0 = ntl * 32;
    int tc = t & 31, tr = t >> 5;
#pragma unroll
    for (int j = 0; j < 4; j++)
        tile[(tr + j * 8) * 33 + tc] = W[(size_t)(k0 + tr + j * 8) * N + n0 + tc];
    __syncthreads();
#pragma unroll
    for (int j = 0; j < 4; j++) {
        int r = tr + j * 8;
        Wt[pk_idx(n0 + r, k0 + tc, K)] = f2bf(tile[tc * 33 + r]);
    }
}

__global__ __launch_bounds__(256) void setupA_kernel(
    const float* __restrict__ x, float* __restrict__ part,
    const float* __restrict__ style,
    const float* __restrict__ Ws, const float* __restrict__ bs,
    float* __restrict__ tmp_s,
    const float* __restrict__ Wq, const float* __restrict__ Wo,
    const float* __restrict__ Wk, const float* __restrict__ Wv,
    const float* __restrict__ Wp2,
    const float* __restrict__ Wf1, const float* __restrict__ Wf2,
    unsigned short* __restrict__ wq_t, unsigned short* __restrict__ wo_t,
    unsigned short* __restrict__ wk_t, unsigned short* __restrict__ wv_t,
    unsigned short* __restrict__ wp2_t,
    unsigned short* __restrict__ wf1_t, unsigned short* __restrict__ wf2_t)
{
    __shared__ float sm[1600];
    const int L = blockIdx.x, t = threadIdx.x;

    if (L < 1024) {
        // ---- GroupNorm partial stats ----------------------------------------
        int bg_ = L >> 4, sub = L & 15;
        const float4* p = (const float4*)(x + bg_ * 262144 + sub * 16384);
        float s = 0.f, q = 0.f;
#pragma unroll
        for (int i = 0; i < 16; i++) {
            float4 v = p[i * 256 + t];
            s += v.x + v.y + v.z + v.w;
            q += v.x * v.x + v.y * v.y + v.z * v.z + v.w * v.w;
        }
#pragma unroll
        for (int off = 32; off; off >>= 1) { s += __shfl_down(s, off); q += __shfl_down(q, off); }
        int lane = t & 63, w = t >> 6;
        if (lane == 0) { sm[w * 2] = s; sm[w * 2 + 1] = q; }
        __syncthreads();
        if (t == 0) {
            part[L * 2]     = sm[0] + sm[2] + sm[4] + sm[6];
            part[L * 2 + 1] = sm[1] + sm[3] + sm[5] + sm[7];
        }
    } else if (L < 1040) {
        // ---- ts = style @ Ws + bs (wave-split-k) -----------------------------
        int b = L - 1024;
        float* st = sm;            // 512
        float* pr = sm + 512;      // 1024
        st[t] = style[b * 512 + t];
        st[256 + t] = style[b * 512 + 256 + t];
        __syncthreads();
        {
            int kc = t >> 6, ln = t & 63;
            float a0 = 0.f, a1 = 0.f, a2 = 0.f, a3 = 0.f;
#pragma unroll 4
            for (int i = kc * 128; i < kc * 128 + 128; i++) {
                float sv = st[i];
                const float* wr = &Ws[(size_t)i * 256];
                a0 += sv * wr[ln];       a1 += sv * wr[64 + ln];
                a2 += sv * wr[128 + ln]; a3 += sv * wr[192 + ln];
            }
            pr[kc * 256 + ln]       = a0; pr[kc * 256 + 64 + ln]  = a1;
            pr[kc * 256 + 128 + ln] = a2; pr[kc * 256 + 192 + ln] = a3;
        }
        __syncthreads();
        tmp_s[b * 256 + t] = pr[t] + pr[256 + t] + pr[512 + t] + pr[768 + t] + bs[t];
    } else if (L < 1104) {
        wtrans_body(Wq, wq_t, 256, 256, L - 1040, t, sm);
    } else if (L < 1168) {
        wtrans_body(Wo, wo_t, 256, 256, L - 1104, t, sm);
    } else if (L < 1232) {
        wtrans_body(Wk, wk_t, 256, 256, L - 1168, t, sm);
    } else if (L < 1296) {
        wtrans_body(Wv, wv_t, 256, 256, L - 1232, t, sm);
    } else if (L < 1360) {
        wtrans_body(Wp2, wp2_t, 256, 256, L - 1296, t, sm);
    } else if (L < 1488) {
        wtrans_body(Wf1, wf1_t, 256, 512, L - 1360, t, sm);
    } else {
        wtrans_body(Wf2, wf2_t, 512, 256, L - 1488, t, sm);
    }
}

// ============================================================================
// setupB: kv (16 blks, MFMA) | pos (128 blks, MFMA) | stylegp (32 blks)
// grid = 16 + 128 + 32 = 176
// ============================================================================
__global__ __launch_bounds__(256) void setupB_kernel(
    const float* __restrict__ tokens, const float* __restrict__ tmp_s,
    const float* __restrict__ ltg, const float* __restrict__ ltb,
    const __bf16* __restrict__ wk_t, const float* __restrict__ bk,
    const __bf16* __restrict__ wv_t, const float* __restrict__ bv,
    unsigned short* __restrict__ kb16, unsigned short* __restrict__ vt16,
    const float* __restrict__ Wp1, const float* __restrict__ bp1,
    const __bf16* __restrict__ wp2_t, const float* __restrict__ bp2,
    float* __restrict__ pos,
    const float* __restrict__ style, const float* __restrict__ Wg,
    const float* __restrict__ bg, float* __restrict__ gp)
{
    __shared__ __align__(16) unsigned char smB[33792];
    const int L = blockIdx.x, t = threadIdx.x;
    const int w = t >> 6, ln = t & 63;
    const int quad = ln >> 4, l16 = ln & 15;
    const f32x4 z4 = {0.f, 0.f, 0.f, 0.f};

    if (L < 16) {
        // ---- kv: token-LN (LDS bf16) + K/V via MFMA, packed stores -----------
        const int b = L;
        __bf16* trb = (__bf16*)smB;    // 64 x 264
        const float ts0 = tmp_s[b * 256 + ln],       ts1 = tmp_s[b * 256 + 64 + ln];
        const float ts2 = tmp_s[b * 256 + 128 + ln], ts3 = tmp_s[b * 256 + 192 + ln];
        const float g0 = ltg[ln],       g1 = ltg[64 + ln];
        const float g2 = ltg[128 + ln], g3 = ltg[192 + ln];
        const float h0 = ltb[ln],       h1 = ltb[64 + ln];
        const float h2 = ltb[128 + ln], h3 = ltb[192 + ln];
        // wave w owns tokens [w*16, w*16+16)
#pragma unroll 4
        for (int j = 0; j < 16; j++) {
            int tok = w * 16 + j;
            float v0 = tokens[tok * 256 + ln]       + ts0;
            float v1 = tokens[tok * 256 + 64 + ln]  + ts1;
            float v2 = tokens[tok * 256 + 128 + ln] + ts2;
            float v3 = tokens[tok * 256 + 192 + ln] + ts3;
            float s = v0 + v1 + v2 + v3;
            float q = v0 * v0 + v1 * v1 + v2 * v2 + v3 * v3;
#pragma unroll
            for (int off = 1; off < 64; off <<= 1) { s += __shfl_xor(s, off); q += __shfl_xor(q, off); }
            float m = s * (1.f / 256.f);
            float var = q * (1.f / 256.f) - m * m;
            float r = rsqrtf(var + EPSF);
            trb[tok * 264 + ln]       = (__bf16)((v0 - m) * r * g0 + h0);
            trb[tok * 264 + 64 + ln]  = (__bf16)((v1 - m) * r * g1 + h1);
            trb[tok * 264 + 128 + ln] = (__bf16)((v2 - m) * r * g2 + h2);
            trb[tok * 264 + 192 + ln] = (__bf16)((v3 - m) * r * g3 + h3);
        }
        __syncthreads();
        // K: wave w = head w; cols = channels, rows = tokens (4 row-tiles)
#pragma unroll
        for (int nt = 0; nt < 4; nt++) {
            int n = w * 64 + nt * 16 + l16;
            f32x4 ac[4] = {z4, z4, z4, z4};
#pragma unroll
            for (int ks = 0; ks < 8; ks++) {
                bf16x8 bvk = ld_bf8(&wk_t[(((w * 4 + nt) * 8 + ks) * 4 + quad) * 128 + l16 * 8]);
#pragma unroll
                for (int rt = 0; rt < 4; rt++)
                    ac[rt] = MFMA16(ld_bf8(&trb[(rt * 16 + l16) * 264 + ks * 32 + quad * 8]), bvk, ac[rt]);
            }
            float bias = bk[n];
            int c64 = nt * 16 + l16;
            int k0c = c64 >> 5, qd = (c64 >> 3) & 3, e = c64 & 7;
#pragma unroll
            for (int rt = 0; rt < 4; rt++)
#pragma unroll
                for (int r = 0; r < 4; r++)
                    kb16[b * 16384 + ((((w * 4 + rt) * 2 + k0c) * 4 + qd) * 16 + (quad * 4 + r)) * 8 + e]
                        = f2bf(ac[rt][r] + bias);
        }
        // V: same A, V weights; packed [b][h][chTile][tok>>5][(tok>>3)&3][ch&15][tok&7]
#pragma unroll
        for (int nt = 0; nt < 4; nt++) {
            int n = w * 64 + nt * 16 + l16;
            f32x4 ac[4] = {z4, z4, z4, z4};
#pragma unroll
            for (int ks = 0; ks < 8; ks++) {
                bf16x8 bvv = ld_bf8(&wv_t[(((w * 4 + nt) * 8 + ks) * 4 + quad) * 128 + l16 * 8]);
#pragma unroll
                for (int rt = 0; rt < 4; rt++)
                    ac[rt] = MFMA16(ld_bf8(&trb[(rt * 16 + l16) * 264 + ks * 32 + quad * 8]), bvv, ac[rt]);
            }
            float bias = bv[n];
#pragma unroll
            for (int rt = 0; rt < 4; rt++)
#pragma unroll
                for (int r = 0; r < 4; r++) {
                    int tok = rt * 16 + quad * 4 + r;
                    vt16[b * 16384 + ((((w * 4 + nt) * 2 + (tok >> 5)) * 4 + ((tok >> 3) & 3)) * 16 + l16) * 8 + (tok & 7)]
                        = f2bf(ac[rt][r] + bias);
                }
        }
    } else if (L < 144) {
        // ---- pos: pe = silu(coords@Wp1+bp1) in LDS bf16; pos = pe@Wp2 + bp2 --
        const int s0 = (L - 16) * 32;
        __bf16* peb = (__bf16*)smB;    // 32 x 264
        {
            float wa = Wp1[t], wb = Wp1[256 + t], bp = bp1[t];
#pragma unroll
            for (int i = 0; i < 32; i++) {
                int sx = s0 + i;
                float gx = -1.f + 2.f * (float)(sx & 63) * (1.f / 63.f);
                float gy = -1.f + 2.f * (float)(sx >> 6) * (1.f / 63.f);
                float h = gx * wa + gy * wb + bp;
                peb[i * 264 + t] = (__bf16)(h / (1.f + __expf(-h)));
            }
        }
        __syncthreads();
#pragma unroll
        for (int nt = 0; nt < 4; nt++) {
            int n = w * 64 + nt * 16 + l16;
            f32x4 a0 = z4, a1 = z4;
#pragma unroll
            for (int ks = 0; ks < 8; ks++) {
                bf16x8 bvw = ld_bf8(&wp2_t[(((w * 4 + nt) * 8 + ks) * 4 + quad) * 128 + l16 * 8]);
                a0 = MFMA16(ld_bf8(&peb[l16 * 264 + ks * 32 + quad * 8]), bvw, a0);
                a1 = MFMA16(ld_bf8(&peb[(16 + l16) * 264 + ks * 32 + quad * 8]), bvw, a1);
            }
            float bp = bp2[n];
#pragma unroll
            for (int r = 0; r < 4; r++) {
                pos[(size_t)(s0 + quad * 4 + r) * 256 + n]      = a0[r] + bp;
                pos[(size_t)(s0 + 16 + quad * 4 + r) * 256 + n] = a1[r] + bp;
            }
        }
    } else {
        // ---- style proj gp: wave-split-k + LDS reduce ------------------------
        int lb = L - 144, b = lb >> 1, role = lb & 1;
        float* st = (float*)smB;            // 512
        float* pr = (float*)smB + 512;      // 1024
        st[t] = style[b * 512 + t];
        st[256 + t] = style[b * 512 + 256 + t];
        __syncthreads();
        {
            int kc = t >> 6;
            float a0 = 0.f, a1 = 0.f, a2 = 0.f, a3 = 0.f;
#pragma unroll 4
            for (int i = kc * 128; i < kc * 128 + 128; i++) {
                float sv = st[i];
                const float* wr = &Wg[(size_t)i * 512 + role * 256];
                a0 += sv * wr[ln];       a1 += sv * wr[64 + ln];
                a2 += sv * wr[128 + ln]; a3 += sv * wr[192 + ln];
            }
            pr[kc * 256 + ln]       = a0; pr[kc * 256 + 64 + ln]  = a1;
            pr[kc * 256 + 128 + ln] = a2; pr[kc * 256 + 192 + ln] = a3;
        }
        __syncthreads();
        int c = role * 256 + t;
        float acc = pr[t] + pr[256 + t] + pr[512 + t] + pr[768 + t];
        gp[b * 512 + c] = acc + bg[c];
    }
}

// ============================================================================
// Mega kernel (EXACT R7 — 145 µs measured). Block = (b, 32-row tile).
// LDS = 35,328 B -> 4 blocks/CU. S4 lazy-A; FFN in two halves via PsB.
// ============================================================================
__global__ __launch_bounds__(256, 4) void mega_kernel(
    const float* __restrict__ x, const float* __restrict__ part,
    const float* __restrict__ pos,
    const __bf16* __restrict__ kb, const __bf16* __restrict__ vt,
    const float* __restrict__ gp,
    const float* __restrict__ lnq_g, const float* __restrict__ lnq_b,
    const float* __restrict__ lnf_g, const float* __restrict__ lnf_b,
    const __bf16* __restrict__ Wq_t, const float* __restrict__ bq,
    const __bf16* __restrict__ Wo_t, const float* __restrict__ bo,
    const __bf16* __restrict__ Wf1_t, const float* __restrict__ bf1,
    const __bf16* __restrict__ Wf2_t, const float* __restrict__ bf2,
    const float* __restrict__ gamma, float* __restrict__ out)
{
    __shared__ __align__(16) unsigned char smraw[35328];
    __bf16* Ab  = (__bf16*)smraw;                 // 32 x 264 bf16 = 16,896 B
    __bf16* PsB = (__bf16*)(smraw + 16896);       // 18,432 B scratch region
    float*  T   = (float*)smraw;                  // overlay: 32 x 268 f32 = 34,304 B
    float* psum   = (float*)(smraw + 16896);      // stats overlays (PsB region)
    float* psq    = psum + 256;
    float* rowred = psum + 512;

    const int blk  = blockIdx.x;        // 2048 = 16 b * 128 tiles
    const int b    = blk >> 7;
    const int s0   = (blk & 127) * 32;
    const int t    = threadIdx.x;
    const int w    = t >> 6;
    const int lane = t & 63;
    const int quad = lane >> 4;
    const int l16  = lane & 15;

    const int woff   = quad * 128 + l16 * 8;
    const int qkbase = w * 16384 + woff;
    const int ffbase = w * 32768 + woff;
    const int kvbase = b * 16384 + w * 4096 + woff;

    const f32x4 z4 = {0.f, 0.f, 0.f, 0.f};

    // ---- prologue: GN stats from part ----------------------------------------
    if (t < 64) {
        int g = t >> 4, sub = t & 15;
        float s = part[((b * 4 + g) * 16 + sub) * 2];
        float q = part[((b * 4 + g) * 16 + sub) * 2 + 1];
#pragma unroll
        for (int off = 8; off; off >>= 1) { s += __shfl_xor(s, off); q += __shfl_xor(q, off); }
        if (sub == 0) {
            float m   = s * (1.f / 262144.f);
            float var = q * (1.f / 262144.f) - m * m;
            psum[g]     = m;
            psum[4 + g] = rsqrtf(var + EPSF);
        }
    }
    __syncthreads();
    const float mg = psum[t >> 6];
    const float rg = psum[4 + (t >> 6)];

    // ---- S1: Ab = bf16(GN(x)+pos); row stats; LN_q in place ------------------
    {
        const float4* xp = (const float4*)(x + (size_t)(b * 256 + t) * 4096 + s0);
        float xv[32];
#pragma unroll
        for (int i = 0; i < 8; i++) {
            float4 v = xp[i];
            xv[4*i] = v.x; xv[4*i+1] = v.y; xv[4*i+2] = v.z; xv[4*i+3] = v.w;
        }
#pragma unroll
        for (int i = 0; i < 32; i++)
            Ab[i * 264 + t] = (__bf16)((xv[i] - mg) * rg + pos[(size_t)(s0 + i) * 256 + t]);
    }
    __syncthreads();
    {
        int sl = t & 31, cg = t >> 5;
        float s = 0.f, q = 0.f;
#pragma unroll
        for (int j = 0; j < 4; j++) {
            bf16x8 v8 = ld_bf8(&Ab[sl * 264 + cg * 32 + j * 8]);
#pragma unroll
            for (int e = 0; e < 8; e++) { float f = (float)v8[e]; s += f; q += f * f; }
        }
        psum[cg * 32 + sl] = s; psq[cg * 32 + sl] = q;
    }
    __syncthreads();
    if (t < 32) {
        float S = 0.f, Q = 0.f;
        for (int p = 0; p < 8; p++) { S += psum[p * 32 + t]; Q += psq[p * 32 + t]; }
        float m = S * (1.f / 256.f);
        float var = Q * (1.f / 256.f) - m * m;
        rowred[t * 2] = m; rowred[t * 2 + 1] = rsqrtf(var + EPSF);
    }
    __syncthreads();
    {
        float gq = lnq_g[t], bqv = lnq_b[t];
#pragma unroll
        for (int i = 0; i < 32; i++) {
            float v = (float)Ab[i * 264 + t];
            Ab[i * 264 + t] = (__bf16)((v - rowred[i * 2]) * rowred[i * 2 + 1] * gq + bqv);
        }
    }
    __syncthreads();

    // ---- S2: q = Ab @ Wq + bq -> Ab ------------------------------------------
    {
        bf16x8 af[2][8];
#pragma unroll
        for (int rt = 0; rt < 2; rt++)
#pragma unroll
            for (int ks = 0; ks < 8; ks++)
                af[rt][ks] = ld_bf8(&Ab[(rt * 16 + l16) * 264 + ks * 32 + quad * 8]);
        __syncthreads();
#pragma unroll
        for (int nt = 0; nt < 4; nt++) {
            int n = w * 64 + nt * 16 + l16;
            f32x4 a0 = z4, a1 = z4;
#pragma unroll
            for (int ks = 0; ks < 8; ks++) {
                bf16x8 bv = ld_bf8(&Wq_t[qkbase + (nt * 8 + ks) * 512]);
                a0 = MFMA16(af[0][ks], bv, a0);
                a1 = MFMA16(af[1][ks], bv, a1);
            }
            float bias = bq[n];
#pragma unroll
            for (int r = 0; r < 4; r++) {
                Ab[(quad * 4 + r) * 264 + n]        = (__bf16)(a0[r] + bias);
                Ab[(16 + quad * 4 + r) * 264 + n]   = (__bf16)(a1[r] + bias);
            }
        }
    }

    // ---- S3: attention, head = w, 32 rows ------------------------------------
    {
        const int h = w;
        __bf16* Psw = PsB + w * 32 * 72;
        bf16x8 qa[2][2];
#pragma unroll
        for (int rt = 0; rt < 2; rt++)
#pragma unroll
            for (int k0 = 0; k0 < 2; k0++)
                qa[rt][k0] = ld_bf8(&Ab[(rt * 16 + l16) * 264 + h * 64 + k0 * 32 + quad * 8]);
        f32x4 sa[2][4];
#pragma unroll
        for (int rt = 0; rt < 2; rt++)
#pragma unroll
            for (int nt = 0; nt < 4; nt++) sa[rt][nt] = z4;
#pragma unroll
        for (int nt = 0; nt < 4; nt++)
#pragma unroll
            for (int k0 = 0; k0 < 2; k0++) {
                bf16x8 kv8 = ld_bf8(&kb[kvbase + (nt * 2 + k0) * 512]);
                sa[0][nt] = MFMA16(qa[0][k0], kv8, sa[0][nt]);
                sa[1][nt] = MFMA16(qa[1][k0], kv8, sa[1][nt]);
            }
#pragma unroll
        for (int rt = 0; rt < 2; rt++)
#pragma unroll
            for (int r = 0; r < 4; r++) {
                float e0 = sa[rt][0][r] * 0.25f, e1 = sa[rt][1][r] * 0.25f;
                float e2 = sa[rt][2][r] * 0.25f, e3 = sa[rt][3][r] * 0.25f;
                float mx = fmaxf(fmaxf(e0, e1), fmaxf(e2, e3));
#pragma unroll
                for (int off = 1; off < 16; off <<= 1) mx = fmaxf(mx, __shfl_xor(mx, off));
                e0 = __expf(e0 - mx); e1 = __expf(e1 - mx);
                e2 = __expf(e2 - mx); e3 = __expf(e3 - mx);
                float sum = e0 + e1 + e2 + e3;
#pragma unroll
                for (int off = 1; off < 16; off <<= 1) sum += __shfl_xor(sum, off);
                float inv = 1.f / sum;
                int row = rt * 16 + quad * 4 + r;
                Psw[row * 72 +  0 + l16] = (__bf16)(e0 * inv);
                Psw[row * 72 + 16 + l16] = (__bf16)(e1 * inv);
                Psw[row * 72 + 32 + l16] = (__bf16)(e2 * inv);
                Psw[row * 72 + 48 + l16] = (__bf16)(e3 * inv);
            }
        bf16x8 pa[2][2];
#pragma unroll
        for (int rt = 0; rt < 2; rt++)
#pragma unroll
            for (int k0 = 0; k0 < 2; k0++)
                pa[rt][k0] = ld_bf8(&Psw[(rt * 16 + l16) * 72 + k0 * 32 + quad * 8]);
#pragma unroll
        for (int nt = 0; nt < 4; nt++) {
            f32x4 o0 = z4, o1 = z4;
#pragma unroll
            for (int k0 = 0; k0 < 2; k0++) {
                bf16x8 vv = ld_bf8(&vt[kvbase + (nt * 2 + k0) * 512]);
                o0 = MFMA16(pa[0][k0], vv, o0);
                o1 = MFMA16(pa[1][k0], vv, o1);
            }
#pragma unroll
            for (int r = 0; r < 4; r++) {
                Ab[(quad * 4 + r) * 264 + h * 64 + nt * 16 + l16]      = (__bf16)o0[r];
                Ab[(16 + quad * 4 + r) * 264 + h * 64 + nt * 16 + l16] = (__bf16)o1[r];
            }
        }
    }
    __syncthreads();

    // ---- S4: sc = Ab @ Wo + bo -> f32 regs (LAZY A) --------------------------
    f32x4 scf[2][4];
    {
#pragma unroll
        for (int nt = 0; nt < 4; nt++) {
            int n = w * 64 + nt * 16 + l16;
            f32x4 a0 = z4, a1 = z4;
#pragma unroll
            for (int ks = 0; ks < 8; ks++) {
                bf16x8 bv = ld_bf8(&Wo_t[qkbase + (nt * 8 + ks) * 512]);
                a0 = MFMA16(ld_bf8(&Ab[l16 * 264 + ks * 32 + quad * 8]), bv, a0);
                a1 = MFMA16(ld_bf8(&Ab[(16 + l16) * 264 + ks * 32 + quad * 8]), bv, a1);
            }
            float bias = bo[n];
#pragma unroll
            for (int r = 0; r < 4; r++) { a0[r] += bias; a1[r] += bias; }
            scf[0][nt] = a0;
            scf[1][nt] = a1;
        }
    }

    // ---- S5: row stats of sc from registers ----------------------------------
    {
#pragma unroll
        for (int rt = 0; rt < 2; rt++)
#pragma unroll
            for (int r = 0; r < 4; r++) {
                float s = scf[rt][0][r] + scf[rt][1][r] + scf[rt][2][r] + scf[rt][3][r];
                float q = scf[rt][0][r] * scf[rt][0][r] + scf[rt][1][r] * scf[rt][1][r]
                        + scf[rt][2][r] * scf[rt][2][r] + scf[rt][3][r] * scf[rt][3][r];
#pragma unroll
                for (int mk = 1; mk < 16; mk <<= 1) { s += __shfl_xor(s, mk); q += __shfl_xor(q, mk); }
                if (l16 == 0) {
                    int row = rt * 16 + quad * 4 + r;
                    psum[row * 4 + w] = s;
                    psq[row * 4 + w]  = q;
                }
            }
    }
    __syncthreads();
    if (t < 32) {
        float S = psum[t * 4] + psum[t * 4 + 1] + psum[t * 4 + 2] + psum[t * 4 + 3];
        float Q = psq[t * 4]  + psq[t * 4 + 1]  + psq[t * 4 + 2]  + psq[t * 4 + 3];
        float m = S * (1.f / 256.f);
        float var = Q * (1.f / 256.f) - m * m;
        rowred[t * 2] = m; rowred[t * 2 + 1] = rsqrtf(var + EPSF);
    }
    __syncthreads();

    // ---- LN_f from registers -> Ab; fold scf+bf2 into acc2 -------------------
    f32x4 acc2[2][4];
    {
        float gf[4], bff[4];
#pragma unroll
        for (int nt = 0; nt < 4; nt++) {
            int n = w * 64 + nt * 16 + l16;
            gf[nt] = lnf_g[n]; bff[nt] = lnf_b[n];
        }
#pragma unroll
        for (int rt = 0; rt < 2; rt++)
#pragma unroll
            for (int r = 0; r < 4; r++) {
                int row = rt * 16 + quad * 4 + r;
                float m = rowred[row * 2], ri = rowred[row * 2 + 1];
#pragma unroll
                for (int nt = 0; nt < 4; nt++) {
                    int n = w * 64 + nt * 16 + l16;
                    Ab[row * 264 + n] = (__bf16)((scf[rt][nt][r] - m) * ri * gf[nt] + bff[nt]);
                }
            }
#pragma unroll
        for (int nt = 0; nt < 4; nt++) {
            float b2 = bf2[w * 64 + nt * 16 + l16];
#pragma unroll
            for (int rt = 0; rt < 2; rt++) {
                acc2[rt][nt] = scf[rt][nt];
#pragma unroll
                for (int r = 0; r < 4; r++) acc2[rt][nt][r] += b2;
            }
        }
    }
    __syncthreads();

    // ---- FFN: two 256-col halves; H-half in PsB; Ab stays live ---------------
    {
        __bf16* H1 = PsB;
#pragma unroll
        for (int hh = 0; hh < 2; hh++) {
#pragma unroll
            for (int nt = 0; nt < 4; nt++) {
                const int tile1 = hh * 16 + w * 4 + nt;
                f32x4 h0 = z4, h1v = z4;
#pragma unroll
                for (int ks = 0; ks < 8; ks++) {
                    bf16x8 bv = ld_bf8(&Wf1_t[(tile1 * 8 + ks) * 512 + woff]);
                    h0  = MFMA16(ld_bf8(&Ab[l16 * 264 + ks * 32 + quad * 8]), bv, h0);
                    h1v = MFMA16(ld_bf8(&Ab[(16 + l16) * 264 + ks * 32 + quad * 8]), bv, h1v);
                }
                const int hc = w * 64 + nt * 16 + l16;
                float b1v = bf1[hh * 256 + hc];
#pragma unroll
                for (int r = 0; r < 4; r++) {
                    float u0 = h0[r] + b1v;
                    float u1 = h1v[r] + b1v;
                    H1[(quad * 4 + r) * 264 + hc]      = (__bf16)(u0 / (1.f + __expf(-u0)));
                    H1[(16 + quad * 4 + r) * 264 + hc] = (__bf16)(u1 / (1.f + __expf(-u1)));
                }
            }
            __syncthreads();
#pragma unroll
            for (int k0 = 0; k0 < 8; k0++) {
                bf16x8 ha0 = ld_bf8(&H1[l16 * 264 + k0 * 32 + quad * 8]);
                bf16x8 ha1 = ld_bf8(&H1[(16 + l16) * 264 + k0 * 32 + quad * 8]);
#pragma unroll
                for (int nt = 0; nt < 4; nt++) {
                    bf16x8 bv = ld_bf8(&Wf2_t[ffbase + (nt * 16 + hh * 8 + k0) * 512]);
                    acc2[0][nt] = MFMA16(ha0, bv, acc2[0][nt]);
                    acc2[1][nt] = MFMA16(ha1, bv, acc2[1][nt]);
                }
            }
            __syncthreads();
        }
    }

    // ---- sc_final -> T (f32 transpose) ---------------------------------------
    {
#pragma unroll
        for (int nt = 0; nt < 4; nt++) {
            int n = w * 64 + nt * 16 + l16;
#pragma unroll
            for (int rt = 0; rt < 2; rt++)
#pragma unroll
                for (int r = 0; r < 4; r++)
                    T[(rt * 16 + quad * 4 + r) * 268 + n] = acc2[rt][nt][r];
        }
    }
    __syncthreads();

    // ---- S6: out = GN(x)*scale + shift + sc*gamma ----------------------------
    {
        const float scl = gp[b * 512 + t];
        const float sft = gp[b * 512 + 256 + t];
        const float gm  = gamma[t];
        const float4* xp = (const float4*)(x + (size_t)(b * 256 + t) * 4096 + s0);
        float4* op = (float4*)(out + (size_t)(b * 256 + t) * 4096 + s0);
#pragma unroll
        for (int ii = 0; ii < 8; ii++) {
            float4 xv = xp[ii];
            float4 o;
            o.x = (xv.x - mg) * rg * scl + sft + T[(ii * 4 + 0) * 268 + t] * gm;
            o.y = (xv.y - mg) * rg * scl + sft + T[(ii * 4 + 1) * 268 + t] * gm;
            o.z = (xv.z - mg) * rg * scl + sft + T[(ii * 4 + 2) * 268 + t] * gm;
            o.w = (xv.w - mg) * rg * scl + sft + T[(ii * 4 + 3) * 268 + t] * gm;
            op[ii] = o;
        }
    }
}

// ============================================================================
extern "C" void kernel_launch(void* const* d_in, const int* in_sizes, int n_in,
                              void* d_out, int out_size, void* d_ws, size_t ws_size,
                              hipStream_t stream) {
    (void)in_sizes; (void)n_in; (void)out_size; (void)ws_size;
    const float* x      = (const float*)d_in[0];
    const float* style  = (const float*)d_in[1];
    const float* Wg     = (const float*)d_in[2];
    const float* bg     = (const float*)d_in[3];
    const float* tokens = (const float*)d_in[4];
    const float* Ws     = (const float*)d_in[5];
    const float* bs     = (const float*)d_in[6];
    const float* Wp1    = (const float*)d_in[7];
    const float* bp1    = (const float*)d_in[8];
    const float* Wp2    = (const float*)d_in[9];
    const float* bp2    = (const float*)d_in[10];
    const float* ln_t_g = (const float*)d_in[11];
    const float* ln_t_b = (const float*)d_in[12];
    const float* ln_q_g = (const float*)d_in[13];
    const float* ln_q_b = (const float*)d_in[14];
    const float* ln_f_g = (const float*)d_in[15];
    const float* ln_f_b = (const float*)d_in[16];
    const float* Wq     = (const float*)d_in[17];
    const float* bq     = (const float*)d_in[18];
    const float* Wk     = (const float*)d_in[19];
    const float* bk     = (const float*)d_in[20];
    const float* Wv     = (const float*)d_in[21];
    const float* bv     = (const float*)d_in[22];
    const float* Wo     = (const float*)d_in[23];
    const float* bo     = (const float*)d_in[24];
    const float* Wf1    = (const float*)d_in[25];
    const float* bf1    = (const float*)d_in[26];
    const float* Wf2    = (const float*)d_in[27];
    const float* bf2    = (const float*)d_in[28];
    const float* gamma  = (const float*)d_in[29];
    float* out = (float*)d_out;

    // d_ws layout (~7.1 MB)
    float* ws = (float*)d_ws;
    float* part  = ws;               // 2048
    float* stats = part  + 2048;     // 128  (unused, layout stability)
    float* gpb   = stats + 128;      // 8192
    float* tmp_s = gpb   + 8192;     // 4096
    float* tokb  = tmp_s + 4096;     // 262144 floats -> carve wk_t/wv_t/wp2_t
    float* posb  = tokb  + 262144;   // 1048576
    unsigned short* wk_t  = (unsigned short*)tokb;             // 65536 ushort
    unsigned short* wv_t  = wk_t + 65536;                      // 65536
    unsigned short* wp2_t = wv_t + 65536;                      // 65536 (total 384KB < 1MB)
    unsigned short* kb16  = (unsigned short*)(posb + 1048576); // 262144
    unsigned short* vt16  = kb16  + 262144;                    // 262144
    unsigned short* wq_t  = vt16  + 262144;                    // 65536
    unsigned short* wo_t  = wq_t  + 65536;                     // 65536
    unsigned short* wf1_t = wo_t  + 65536;                     // 131072
    unsigned short* wf2_t = wf1_t + 131072;                    // 131072

    setupA_kernel<<<1616, 256, 0, stream>>>(x, part, style, Ws, bs, tmp_s,
                                            Wq, Wo, Wk, Wv, Wp2, Wf1, Wf2,
                                            wq_t, wo_t, wk_t, wv_t, wp2_t, wf1_t, wf2_t);
    setupB_kernel<<<176, 256, 0, stream>>>(tokens, tmp_s, ln_t_g, ln_t_b,
                                           (const __bf16*)wk_t, bk,
                                           (const __bf16*)wv_t, bv,
                                           kb16, vt16,
                                           Wp1, bp1, (const __bf16*)wp2_t, bp2, posb,
                                           style, Wg, bg, gpb);
    mega_kernel<<<2048, 256, 0, stream>>>(x, part, posb,
                                          (const __bf16*)kb16, (const __bf16*)vt16, gpb,
                                          ln_q_g, ln_q_b, ln_f_g, ln_f_b,
                                          (const __bf16*)wq_t, bq,
                                          (const __bf16*)wo_t, bo,
                                          (const __bf16*)wf1_t, bf1,
                                          (const __bf16*)wf2_t, bf2,
                                          gamma, out);
}